// Round 2
// baseline (796.884 us; speedup 1.0000x reference)
//
#include <hip/hip_runtime.h>

typedef __attribute__((ext_vector_type(4))) float f32x4;
typedef __attribute__((ext_vector_type(16))) float f32x16;
typedef __attribute__((ext_vector_type(8))) short bf16x8;

#define BK 64
#define SROW 72   // LDS row stride in bf16 elems (64 + 8 pad) = 144 B
#define GRID 512
#define NTHR 512

__device__ __forceinline__ unsigned pack_hi(unsigned ua, unsigned ub) {
    // bf16(a) | bf16(b) << 16, truncation rounding
    return (ua >> 16) | (ub & 0xffff0000u);
}

// ws layout (floats): [0 .. 65535]  colsum partials  [GRID][128]
//                     [65536 .. ]   covh partials    [GRID][4]  (h=0..2 used)
__global__ __launch_bounds__(NTHR, 4)
void mainK(const float* __restrict__ x, const float* __restrict__ w_cov,
           float* __restrict__ ws, int nchunks)
{
    __shared__ short ht[128][SROW];
    __shared__ short lt[128][SROW];
    __shared__ float red[8][4];

    const int tid  = threadIdx.x;
    const int lane = tid & 63;
    const int wave = tid >> 6;
    const int c0   = 4 * (tid >> 4);   // column base 0..124
    const int k0   = 2 * (tid & 15);   // row-pair base 0..30

    const int frc = lane & 31;   // row/col within 32x32 tile
    const int frg = lane >> 5;   // k-group

    f32x16 acc[4];
    #pragma unroll
    for (int j = 0; j < 4; ++j)
        #pragma unroll
        for (int r = 0; r < 16; ++r) acc[j][r] = 0.0f;

    float csum[4] = {0.f, 0.f, 0.f, 0.f};

    const bool isGh = (wave < 4);
    const int e0 = 32 * (wave & 3);

    int chunk = blockIdx.x;
    f32x4 v0, v1, v2, v3;
    {
        const float* p = x + (size_t)chunk * (BK * 128) + c0;
        v0 = *(const f32x4*)(p + (size_t)(k0     ) * 128);
        v1 = *(const f32x4*)(p + (size_t)(k0 + 1 ) * 128);
        v2 = *(const f32x4*)(p + (size_t)(k0 + 32) * 128);
        v3 = *(const f32x4*)(p + (size_t)(k0 + 33) * 128);
    }

    while (true) {
        __syncthreads();  // previous iteration's LDS readers done
        #pragma unroll
        for (int i = 0; i < 4; ++i) {
            float a = v0[i], b = v1[i], c = v2[i], d = v3[i];
            csum[i] += (a + b) + (c + d);
            unsigned ua = __float_as_uint(a), ub = __float_as_uint(b);
            unsigned uc = __float_as_uint(c), ud = __float_as_uint(d);
            unsigned la = __float_as_uint(a - __uint_as_float(ua & 0xffff0000u));
            unsigned lb = __float_as_uint(b - __uint_as_float(ub & 0xffff0000u));
            unsigned lc = __float_as_uint(c - __uint_as_float(uc & 0xffff0000u));
            unsigned ld = __float_as_uint(d - __uint_as_float(ud & 0xffff0000u));
            *(unsigned*)&ht[c0 + i][k0     ] = pack_hi(ua, ub);
            *(unsigned*)&ht[c0 + i][k0 + 32] = pack_hi(uc, ud);
            *(unsigned*)&lt[c0 + i][k0     ] = pack_hi(la, lb);
            *(unsigned*)&lt[c0 + i][k0 + 32] = pack_hi(lc, ld);
        }

        const int next = chunk + GRID;
        const bool hasNext = next < nchunks;
        if (hasNext) {  // issue prefetch before the barrier; v already consumed
            const float* p = x + (size_t)next * (BK * 128) + c0;
            v0 = *(const f32x4*)(p + (size_t)(k0     ) * 128);
            v1 = *(const f32x4*)(p + (size_t)(k0 + 1 ) * 128);
            v2 = *(const f32x4*)(p + (size_t)(k0 + 32) * 128);
            v3 = *(const f32x4*)(p + (size_t)(k0 + 33) * 128);
        }
        __syncthreads();  // LDS writes visible

        #pragma unroll
        for (int ks = 0; ks < 4; ++ks) {
            const int kb = ks * 16 + 8 * frg;
            if (isGh) {
                bf16x8 f0 = *(const bf16x8*)&ht[ 0 + frc][kb];
                bf16x8 f1 = *(const bf16x8*)&ht[32 + frc][kb];
                bf16x8 f2 = *(const bf16x8*)&ht[64 + frc][kb];
                bf16x8 f3 = *(const bf16x8*)&ht[96 + frc][kb];
                bf16x8 fa = (e0 == 0) ? f0 : (e0 == 32) ? f1 : (e0 == 64) ? f2 : f3;
                acc[0] = __builtin_amdgcn_mfma_f32_32x32x16_bf16(fa, f0, acc[0], 0, 0, 0);
                acc[1] = __builtin_amdgcn_mfma_f32_32x32x16_bf16(fa, f1, acc[1], 0, 0, 0);
                acc[2] = __builtin_amdgcn_mfma_f32_32x32x16_bf16(fa, f2, acc[2], 0, 0, 0);
                acc[3] = __builtin_amdgcn_mfma_f32_32x32x16_bf16(fa, f3, acc[3], 0, 0, 0);
            } else {
                bf16x8 fa = *(const bf16x8*)&ht[e0 + frc][kb];
                bf16x8 f0 = *(const bf16x8*)&lt[ 0 + frc][kb];
                bf16x8 f1 = *(const bf16x8*)&lt[32 + frc][kb];
                bf16x8 f2 = *(const bf16x8*)&lt[64 + frc][kb];
                bf16x8 f3 = *(const bf16x8*)&lt[96 + frc][kb];
                acc[0] = __builtin_amdgcn_mfma_f32_32x32x16_bf16(fa, f0, acc[0], 0, 0, 0);
                acc[1] = __builtin_amdgcn_mfma_f32_32x32x16_bf16(fa, f1, acc[1], 0, 0, 0);
                acc[2] = __builtin_amdgcn_mfma_f32_32x32x16_bf16(fa, f2, acc[2], 0, 0, 0);
                acc[3] = __builtin_amdgcn_mfma_f32_32x32x16_bf16(fa, f3, acc[3], 0, 0, 0);
            }
        }

        if (!hasNext) break;
        chunk = next;
    }

    // ---- epilogue: contract partial Gram with w_cov in registers ----
    // G = Gh + Ghl + Ghl^T  =>  Gh entries use w_cov[e,t,:]; Ghl entries use
    // w_cov[e,t,:] + w_cov[t,e,:].  No global G materialization, no atomics.
    float wsum0 = 0.f, wsum1 = 0.f, wsum2 = 0.f;
    #pragma unroll
    for (int j = 0; j < 4; ++j)
        #pragma unroll
        for (int r = 0; r < 16; ++r) {
            const int row = e0 + (r & 3) + 8 * (r >> 2) + 4 * frg;  // C/D layout (m74/m101)
            const int col = 32 * j + frc;
            const float g = acc[j][r];
            const float* wp = w_cov + 3 * (row * 128 + col);
            float w0 = wp[0], w1 = wp[1], w2 = wp[2];
            if (!isGh) {
                const float* wq = w_cov + 3 * (col * 128 + row);
                w0 += wq[0]; w1 += wq[1]; w2 += wq[2];
            }
            wsum0 += g * w0; wsum1 += g * w1; wsum2 += g * w2;
        }
    #pragma unroll
    for (int off = 32; off > 0; off >>= 1) {
        wsum0 += __shfl_down(wsum0, off);
        wsum1 += __shfl_down(wsum1, off);
        wsum2 += __shfl_down(wsum2, off);
    }
    if (lane == 0) { red[wave][0] = wsum0; red[wave][1] = wsum1; red[wave][2] = wsum2; }
    __syncthreads();
    if (tid == 0) {
        float s0 = 0.f, s1 = 0.f, s2 = 0.f;
        for (int w = 0; w < 8; ++w) { s0 += red[w][0]; s1 += red[w][1]; s2 += red[w][2]; }
        float* wc = ws + GRID * 128 + (size_t)blockIdx.x * 4;
        wc[0] = s0; wc[1] = s1; wc[2] = s2;
    }

    // ---- column sums: reduce the 16 threads sharing c0, non-atomic slice write ----
    #pragma unroll
    for (int i = 0; i < 4; ++i) {
        float s = csum[i];
        #pragma unroll
        for (int off = 1; off < 16; off <<= 1) s += __shfl_xor(s, off);
        csum[i] = s;  // all 16 lanes in the group now hold the total
    }
    if ((lane & 15) == 0) {
        f32x4 st = { csum[0], csum[1], csum[2], csum[3] };
        *(f32x4*)(ws + (size_t)blockIdx.x * 128 + c0) = st;
    }
}

__global__ __launch_bounds__(NTHR)
void finishK(const float* __restrict__ ws,
             const float* __restrict__ w_mu, const float* __restrict__ w_cov,
             const float* __restrict__ w_mu_out, const float* __restrict__ w_cov_out,
             const float* __restrict__ b_mu, const float* __restrict__ b_cov,
             float* __restrict__ out, float invN)
{
    __shared__ float tmp[4][128];
    __shared__ float lmu[128];
    __shared__ float red[8][12];

    const int tid = threadIdx.x;

    // 1) reduce column-sum partials -> mu
    {
        const int c = tid & 127, q = tid >> 7;
        float s = 0.f;
        for (int b = q; b < GRID; b += 4) s += ws[b * 128 + c];
        tmp[q][c] = s;
    }
    __syncthreads();
    if (tid < 128)
        lmu[tid] = (tmp[0][tid] + tmp[1][tid] + tmp[2][tid] + tmp[3][tid]) * invN;
    __syncthreads();

    // 2) covh block partials (GRID == NTHR: one per thread)
    const float* wc = ws + GRID * 128;
    float c0s = wc[tid * 4 + 0];
    float c1s = wc[tid * 4 + 1];
    float c2s = wc[tid * 4 + 2];

    // 3) mu-quadratic correction:  q_h = sum_et mu_e mu_t w_cov[e,t,h]
    float q0 = 0.f, q1 = 0.f, q2 = 0.f;
    for (int p = tid; p < 16384; p += NTHR) {
        const int e = p >> 7, t = p & 127;
        const float m = lmu[e] * lmu[t];
        const float* wp = w_cov + 3 * p;
        q0 += m * wp[0]; q1 += m * wp[1]; q2 += m * wp[2];
    }

    // 4) mu path
    float m0 = 0.f, m1 = 0.f, m2 = 0.f;
    if (tid < 128) {
        const float mv = lmu[tid];
        m0 = mv * w_mu[3 * tid + 0];
        m1 = mv * w_mu[3 * tid + 1];
        m2 = mv * w_mu[3 * tid + 2];
    }

    // 5) reduce 9 partials
    #pragma unroll
    for (int off = 32; off > 0; off >>= 1) {
        c0s += __shfl_down(c0s, off); c1s += __shfl_down(c1s, off); c2s += __shfl_down(c2s, off);
        q0  += __shfl_down(q0,  off); q1  += __shfl_down(q1,  off); q2  += __shfl_down(q2,  off);
        m0  += __shfl_down(m0,  off); m1  += __shfl_down(m1,  off); m2  += __shfl_down(m2,  off);
    }
    const int lane = tid & 63, wave = tid >> 6;
    if (lane == 0) {
        red[wave][0] = c0s; red[wave][1] = c1s; red[wave][2] = c2s;
        red[wave][3] = q0;  red[wave][4] = q1;  red[wave][5] = q2;
        red[wave][6] = m0;  red[wave][7] = m1;  red[wave][8] = m2;
    }
    __syncthreads();
    if (tid == 0) {
        float A[9] = {0,0,0,0,0,0,0,0,0};
        for (int w = 0; w < 8; ++w)
            for (int q = 0; q < 9; ++q) A[q] += red[w][q];
        float r = 0.f;
        for (int h = 0; h < 3; ++h) {
            float ch = A[h] * invN - A[3 + h] + b_cov[h];
            float mh = A[6 + h] + b_mu[h];
            ch = fmaxf(ch, 0.2f * ch);   // lrelu, LEAK=0.2
            mh = fmaxf(mh, 0.2f * mh);
            r += mh * w_mu_out[h] + ch * w_cov_out[h];
        }
        out[0] = r;
    }
}

extern "C" void kernel_launch(void* const* d_in, const int* in_sizes, int n_in,
                              void* d_out, int out_size, void* d_ws, size_t ws_size,
                              hipStream_t stream) {
    const float* x         = (const float*)d_in[0];
    const float* w_mu      = (const float*)d_in[1];
    const float* w_cov     = (const float*)d_in[2];
    const float* w_mu_out  = (const float*)d_in[3];
    const float* w_cov_out = (const float*)d_in[4];
    const float* b_mu      = (const float*)d_in[5];
    const float* b_cov     = (const float*)d_in[6];
    float* out = (float*)d_out;
    float* ws  = (float*)d_ws;

    const int N = in_sizes[0] / 128;   // 1,000,000
    const int nchunks = N / BK;        // 15,625 (exact)

    mainK<<<GRID, NTHR, 0, stream>>>(x, w_cov, ws, nchunks);
    finishK<<<1, NTHR, 0, stream>>>(ws, w_mu, w_cov, w_mu_out, w_cov_out,
                                    b_mu, b_cov, out, 1.0f / (float)N);
}